// Round 1
// baseline (1046.340 us; speedup 1.0000x reference)
//
#include <hip/hip_runtime.h>

typedef unsigned short u16;
typedef __attribute__((ext_vector_type(8))) short bf16x8;
typedef __attribute__((ext_vector_type(4))) float f32x4;

#define HI 256
#define WI 256
#define CI 64
#define OC 128
#define HO 128
#define WO 128
#define NB 8
#define KC 576           // 64*9
#define KCP 584          // padded (+8 bf16 = 16B) to break LDS bank stride
#define TW 16            // pixels per block (one MFMA M-tile)

static __device__ __forceinline__ u16 f2bf(float f) {
    union { float f; unsigned u; } v; v.f = f;
    unsigned r = (v.u + 0x7FFFu + ((v.u >> 16) & 1u)) >> 16;   // RNE
    return (u16)r;
}

// ---------------- weight fp32 -> bf16 (padded K) ----------------
__global__ void k_wconv(const float* __restrict__ w, u16* __restrict__ wbf) {
    int i = blockIdx.x * 256 + threadIdx.x;
    if (i >= OC * KCP) return;
    int oc = i / KCP, kc = i - oc * KCP;
    float v = (kc < KC) ? w[oc * KC + kc] : 0.f;
    wbf[i] = f2bf(v);
}

// ---------------- offset conv: x (B,64,256,256) -> om (B,27,128,128) ----------------
// block 256 = 128 wo x 2 ch-halves; each thread does 4 channels. grid (4, HO, NB)
__global__ __launch_bounds__(256) void k_off(const float* __restrict__ x,
                                             const float* __restrict__ ow,
                                             const float* __restrict__ ob,
                                             float* __restrict__ om) {
    const int t = threadIdx.x;
    const int wo = t & 127;
    const int chh = t >> 7;                   // wave-uniform
    const int chbase = blockIdx.x * 8 + chh * 4;
    const int ho = blockIdx.y, b = blockIdx.z;
    const int hy = ho * 2 - 1, wxx = wo * 2 - 1;

    int ry[3], cx[3]; bool rv[3], cv[3];
    #pragma unroll
    for (int e = 0; e < 3; ++e) {
        int y = hy + e;  rv[e] = (y >= 0) && (y < HI);  ry[e] = (y < 0 ? 0 : (y > HI-1 ? HI-1 : y)) * WI;
        int xx = wxx + e; cv[e] = (xx >= 0) && (xx < WI); cx[e] = (xx < 0 ? 0 : (xx > WI-1 ? WI-1 : xx));
    }
    float acc[4];
    #pragma unroll
    for (int j = 0; j < 4; ++j) acc[j] = (chbase + j < 27) ? ob[chbase + j] : 0.f;

    const float* xb = x + (size_t)b * CI * HI * WI;
    for (int c = 0; c < CI; ++c) {
        const float* xc = xb + c * (HI * WI);
        float xv[9];
        #pragma unroll
        for (int yy = 0; yy < 3; ++yy)
            #pragma unroll
            for (int xxi = 0; xxi < 3; ++xxi)
                xv[yy * 3 + xxi] = (rv[yy] && cv[xxi]) ? xc[ry[yy] + cx[xxi]] : 0.f;
        #pragma unroll
        for (int j = 0; j < 4; ++j) {
            int ch = chbase + j;
            if (ch < 27) {
                const float* wc = ow + (ch * CI + c) * 9;
                #pragma unroll
                for (int e = 0; e < 9; ++e) acc[j] += xv[e] * wc[e];
            }
        }
    }
    #pragma unroll
    for (int j = 0; j < 4; ++j) {
        int ch = chbase + j;
        if (ch < 27) om[(((size_t)b * 27 + ch) * HO + ho) * WO + wo] = acc[j];
    }
}

// ---------------- main: sample+mask -> LDS (bf16) -> MFMA einsum ----------------
// block 256 threads = 4 waves; tile: TW=16 px  x  128 oc. grid (WO/TW, HO, NB)
__global__ __launch_bounds__(256) void k_main(const float* __restrict__ x,
                                              const float* __restrict__ om,
                                              const u16* __restrict__ wbf,
                                              const float* __restrict__ bias,
                                              float* __restrict__ out) {
    __shared__ u16 s[TW * KCP];
    __shared__ int   ly0[144], ly1[144], lx0[144], lx1[144];
    __shared__ float lw00[144], lw01[144], lw10[144], lw11[144];

    const int t = threadIdx.x;
    const int wo0 = blockIdx.x * TW;
    const int ho = blockIdx.y;
    const int b = blockIdx.z;

    // ---- precompute per (px,k): clamped corner coords + validity*mask-folded weights
    if (t < 144) {
        const int p = t;
        const int px_id = p / 9, k = p - px_id * 9;
        const int wo = wo0 + px_id;
        const size_t base = ((size_t)b * 27) * (HO * WO) + ho * WO + wo;
        float oxv = om[base + (size_t)k * (HO * WO)];
        float oyv = om[base + (size_t)(9 + k) * (HO * WO)];
        float omm = om[base + (size_t)(18 + k) * (HO * WO)];
        float m = 1.f / (1.f + __expf(-omm));
        float py  = oyv + (float)(k / 3) + (float)(ho * 2 - 1);
        float pxf = oxv + (float)(k % 3) + (float)(wo * 2 - 1);
        float fy = floorf(py), fx = floorf(pxf);
        float wy1 = py - fy, wx1 = pxf - fx;
        float wy0 = 1.f - wy1, wx0 = 1.f - wx1;
        int y0 = (int)fy, x0i = (int)fx;
        int y1 = y0 + 1, x1i = x0i + 1;
        bool vy0 = (y0 >= 0) && (y0 < HI), vy1 = (y1 >= 0) && (y1 < HI);
        bool vx0 = (x0i >= 0) && (x0i < WI), vx1 = (x1i >= 0) && (x1i < WI);
        lw00[p] = (vy0 && vx0) ? wy0 * wx0 * m : 0.f;
        lw01[p] = (vy0 && vx1) ? wy0 * wx1 * m : 0.f;
        lw10[p] = (vy1 && vx0) ? wy1 * wx0 * m : 0.f;
        lw11[p] = (vy1 && vx1) ? wy1 * wx1 * m : 0.f;
        ly0[p] = (y0 < 0 ? 0 : (y0 > HI-1 ? HI-1 : y0)) * WI;
        ly1[p] = (y1 < 0 ? 0 : (y1 > HI-1 ? HI-1 : y1)) * WI;
        lx0[p] = (x0i < 0 ? 0 : (x0i > WI-1 ? WI-1 : x0i));
        lx1[p] = (x1i < 0 ? 0 : (x1i > WI-1 ? WI-1 : x1i));
    }
    __syncthreads();

    // ---- phase A: bilinear gather x, apply folded mask-weights, store bf16 to LDS
    const float* xb = x + (size_t)b * CI * HI * WI;
    #pragma unroll 4
    for (int it = 0; it < 36; ++it) {              // 36*256 = 9216 = 16px*9k*64c
        int i = t + it * 256;
        int c = i / 144;
        int p = i - c * 144;
        int px_id = p / 9, k = p - px_id * 9;
        const float* xc = xb + c * (HI * WI);
        int r0 = ly0[p], r1 = ly1[p], c0 = lx0[p], c1 = lx1[p];
        float v = lw00[p] * xc[r0 + c0] + lw01[p] * xc[r0 + c1]
                + lw10[p] * xc[r1 + c0] + lw11[p] * xc[r1 + c1];
        s[px_id * KCP + c * 9 + k] = f2bf(v);
    }
    __syncthreads();

    // ---- phase B: 16px x 128oc GEMM over K=576 via mfma_f32_16x16x32_bf16
    const int lane = t & 63, wv = t >> 6;
    const int q = lane >> 4, l15 = lane & 15;
    const u16* sp  = &s[l15 * KCP + q * 8];
    const int oc0 = wv * 32 + l15;
    const int oc1 = oc0 + 16;
    const u16* wp0 = wbf + oc0 * KCP + q * 8;
    const u16* wp1 = wbf + oc1 * KCP + q * 8;
    f32x4 acc0 = {0.f, 0.f, 0.f, 0.f};
    f32x4 acc1 = {0.f, 0.f, 0.f, 0.f};
    #pragma unroll
    for (int kt = 0; kt < 18; ++kt) {
        bf16x8 a  = *(const bf16x8*)(sp  + kt * 32);
        bf16x8 b0 = *(const bf16x8*)(wp0 + kt * 32);
        bf16x8 b1 = *(const bf16x8*)(wp1 + kt * 32);
        acc0 = __builtin_amdgcn_mfma_f32_16x16x32_bf16(a, b0, acc0, 0, 0, 0);
        acc1 = __builtin_amdgcn_mfma_f32_16x16x32_bf16(a, b1, acc1, 0, 0, 0);
    }
    // D layout: col(=oc)=lane&15, row(=px)=q*4+reg -> lane stores 4 consecutive px
    const float bi0 = bias[oc0], bi1 = bias[oc1];
    const int px = q * 4;
    float* op0 = out + (((size_t)b * OC + oc0) * HO + ho) * WO + wo0 + px;
    float* op1 = out + (((size_t)b * OC + oc1) * HO + ho) * WO + wo0 + px;
    *(float4*)op0 = make_float4(acc0[0] + bi0, acc0[1] + bi0, acc0[2] + bi0, acc0[3] + bi0);
    *(float4*)op1 = make_float4(acc1[0] + bi1, acc1[1] + bi1, acc1[2] + bi1, acc1[3] + bi1);
}

extern "C" void kernel_launch(void* const* d_in, const int* in_sizes, int n_in,
                              void* d_out, int out_size, void* d_ws, size_t ws_size,
                              hipStream_t stream) {
    const float* x        = (const float*)d_in[0];
    const float* offset_w = (const float*)d_in[1];
    const float* offset_b = (const float*)d_in[2];
    const float* weight   = (const float*)d_in[3];
    const float* bias     = (const float*)d_in[4];
    float* out = (float*)d_out;

    u16*   wbf = (u16*)d_ws;                                  // 128*584*2 = 149,504 B
    float* om  = (float*)((char*)d_ws + 151552);              // 8*27*128*128*4 = 14.16 MB

    hipLaunchKernelGGL(k_wconv, dim3((OC * KCP + 255) / 256), dim3(256), 0, stream, weight, wbf);
    hipLaunchKernelGGL(k_off,   dim3(4, HO, NB),  dim3(256), 0, stream, x, offset_w, offset_b, om);
    hipLaunchKernelGGL(k_main,  dim3(WO / TW, HO, NB), dim3(256), 0, stream, x, om, wbf, bias, out);
}

// Round 4
// 626.618 us; speedup vs baseline: 1.6698x; 1.6698x over previous
//
#include <hip/hip_runtime.h>

typedef unsigned short u16;
typedef __attribute__((ext_vector_type(8))) short bf16x8;
typedef __attribute__((ext_vector_type(8))) unsigned short u16x8;
typedef __attribute__((ext_vector_type(4))) float f32x4;

#define HI 256
#define WI 256
#define CI 64
#define OC 128
#define HO 128
#define WO 128
#define NB 8
#define KC 576
#define KCP 584          // +8 pad to break LDS bank stride
#define TW 16            // k_main (r0) pixel tile

static __device__ __forceinline__ u16 f2bf(float f) {   // RNE
    union { float f; unsigned u; } v; v.f = f;
    return (u16)((v.u + 0x7FFFu + ((v.u >> 16) & 1u)) >> 16);
}
static __device__ __forceinline__ float bf2f(u16 h) {
    union { unsigned u; float f; } v; v.u = ((unsigned)h) << 16;
    return v.f;
}

// ---- weights: wbf (main, r0 order kc=c*9+k), wob (offset, r3 order kc=k*64+c) ----
__global__ __launch_bounds__(256) void k_wconv(const float* __restrict__ w,
                                               const float* __restrict__ ow,
                                               u16* __restrict__ wbf, u16* __restrict__ wob) {
    int i = blockIdx.x * 256 + threadIdx.x;
    const int NW = OC * KCP;
    if (i < NW) {
        int oc = i / KCP, kc = i - oc * KCP;
        float v = (kc < KC) ? w[oc * KC + kc] : 0.f;       // flat reshape: kc = c*9+k
        wbf[i] = f2bf(v);
    } else {
        int i2 = i - NW;
        if (i2 < 32 * KCP) {
            int oc = i2 / KCP, kc = i2 - oc * KCP;
            float v = 0.f;
            if (oc < 27 && kc < KC) { int k = kc >> 6, c = kc & 63; v = ow[(oc * CI + c) * 9 + k]; }
            wob[i2] = f2bf(v);
        }
    }
}

// ---- transpose: x[b][c][h][w] fp32 -> xT[bz][h][w][c] bf16 ----
__global__ __launch_bounds__(256) void k_tr(const float* __restrict__ x, u16* __restrict__ xT, int b0) {
    __shared__ u16 tile[64 * 68];
    const int t = threadIdx.x;
    const int w0 = blockIdx.x * 64;
    const int h  = blockIdx.y;
    const int bz = blockIdx.z;
    const float* xp = x + ((size_t)(b0 + bz) * CI) * (HI * WI) + h * WI + w0;
    #pragma unroll
    for (int i = 0; i < 4; ++i) {
        int c = i * 16 + (t >> 4);
        int w = (t & 15) * 4;
        float4 v = *(const float4*)(xp + (size_t)c * (HI * WI) + w);
        tile[(w + 0) * 68 + c] = f2bf(v.x);
        tile[(w + 1) * 68 + c] = f2bf(v.y);
        tile[(w + 2) * 68 + c] = f2bf(v.z);
        tile[(w + 3) * 68 + c] = f2bf(v.w);
    }
    __syncthreads();
    u16* op = xT + (size_t)bz * (HI * WI * CI) + ((size_t)h * WI + w0) * CI;
    #pragma unroll
    for (int j = 0; j < 4; ++j) {
        int w = j * 16 + (t >> 4);
        int c = (t & 15) * 4;
        *(ushort4*)(op + (size_t)w * CI + c) = *(const ushort4*)&tile[w * 68 + c];
    }
}

// ---- offset conv via MFMA: xT -> om[bz][27][ho][wo] fp32 (r3 structure) ----
__global__ __launch_bounds__(256) void k_off(const u16* __restrict__ xT,
                                             const u16* __restrict__ wob,
                                             const float* __restrict__ ob,
                                             float* __restrict__ om) {
    __shared__ u16 s[32 * KCP];
    __shared__ int atab[288];
    __shared__ float red[2][2][64][4];
    const int t = threadIdx.x;
    const int wo0 = blockIdx.x * 32;
    const int ho = blockIdx.y;
    const int bz = blockIdx.z;
    const u16* xb = xT + (size_t)bz * (HI * WI * CI);

    for (int p = t; p < 288; p += 256) {
        int px = p / 9, k = p - px * 9;
        int ky = k / 3, kx = k - ky * 3;
        int y  = ho * 2 - 1 + ky;
        int xx = (wo0 + px) * 2 - 1 + kx;
        bool valid = ((unsigned)y < HI) && ((unsigned)xx < WI);
        atab[p] = valid ? (y * WI + xx) * CI : -1;
    }
    __syncthreads();

    #pragma unroll 3
    for (int it = 0; it < 9; ++it) {
        int idx = it * 256 + t;
        int p = idx >> 3, c8 = idx & 7;
        int a = atab[p];
        u16x8 v = {0, 0, 0, 0, 0, 0, 0, 0};
        if (a >= 0) v = *(const u16x8*)(xb + a + c8 * 8);
        int px = p / 9, k = p - px * 9;
        *(u16x8*)&s[px * KCP + k * 64 + c8 * 8] = v;
    }
    __syncthreads();

    const int lane = t & 63, wv = t >> 6;
    const int q = lane >> 4, l15 = lane & 15;
    const int ph = wv & 1, kh = wv >> 1;
    const u16* sp  = &s[(ph * 16 + l15) * KCP + kh * 288 + q * 8];
    const u16* wp0 = wob + l15 * KCP + kh * 288 + q * 8;
    const u16* wp1 = wob + (16 + l15) * KCP + kh * 288 + q * 8;
    f32x4 acc0 = {0.f, 0.f, 0.f, 0.f}, acc1 = {0.f, 0.f, 0.f, 0.f};
    #pragma unroll
    for (int kt = 0; kt < 9; ++kt) {
        bf16x8 a  = *(const bf16x8*)(sp  + kt * 32);
        bf16x8 b0 = *(const bf16x8*)(wp0 + kt * 32);
        bf16x8 b1 = *(const bf16x8*)(wp1 + kt * 32);
        acc0 = __builtin_amdgcn_mfma_f32_16x16x32_bf16(a, b0, acc0, 0, 0, 0);
        acc1 = __builtin_amdgcn_mfma_f32_16x16x32_bf16(a, b1, acc1, 0, 0, 0);
    }
    if (kh == 1) {
        #pragma unroll
        for (int r = 0; r < 4; ++r) { red[ph][0][lane][r] = acc0[r]; red[ph][1][lane][r] = acc1[r]; }
    }
    __syncthreads();
    if (kh == 0) {
        #pragma unroll
        for (int r = 0; r < 4; ++r) { acc0[r] += red[ph][0][lane][r]; acc1[r] += red[ph][1][lane][r]; }
        const int wo = wo0 + ph * 16 + q * 4;
        float bv0 = ob[l15];
        float* o0 = om + ((size_t)(bz * 27 + l15) * HO + ho) * WO + wo;
        *(float4*)o0 = make_float4(acc0[0] + bv0, acc0[1] + bv0, acc0[2] + bv0, acc0[3] + bv0);
        if (l15 < 11) {
            float bv1 = ob[16 + l15];
            float* o1 = om + ((size_t)(bz * 27 + 16 + l15) * HO + ho) * WO + wo;
            *(float4*)o1 = make_float4(acc1[0] + bv1, acc1[1] + bv1, acc1[2] + bv1, acc1[3] + bv1);
        }
    }
}

// ---- main (ROUND-0 VERBATIM, known-good): fp32 NCHW gathers, TW=16, kc=c*9+k ----
__global__ __launch_bounds__(256) void k_main(const float* __restrict__ x,
                                              const float* __restrict__ om,
                                              const u16* __restrict__ wbf,
                                              const float* __restrict__ bias,
                                              float* __restrict__ out, int b0) {
    __shared__ u16 s[TW * KCP];
    __shared__ int   ly0[144], ly1[144], lx0[144], lx1[144];
    __shared__ float lw00[144], lw01[144], lw10[144], lw11[144];

    const int t = threadIdx.x;
    const int wo0 = blockIdx.x * TW;
    const int ho = blockIdx.y;
    const int bz = blockIdx.z;
    const int b = b0 + bz;

    if (t < 144) {
        const int p = t;
        const int px_id = p / 9, k = p - px_id * 9;
        const int wo = wo0 + px_id;
        const size_t base = ((size_t)bz * 27) * (HO * WO) + ho * WO + wo;
        float oxv = om[base + (size_t)k * (HO * WO)];
        float oyv = om[base + (size_t)(9 + k) * (HO * WO)];
        float omm = om[base + (size_t)(18 + k) * (HO * WO)];
        float m = 1.f / (1.f + __expf(-omm));
        float py  = oyv + (float)(k / 3) + (float)(ho * 2 - 1);
        float pxf = oxv + (float)(k % 3) + (float)(wo * 2 - 1);
        float fy = floorf(py), fx = floorf(pxf);
        float wy1 = py - fy, wx1 = pxf - fx;
        float wy0 = 1.f - wy1, wx0 = 1.f - wx1;
        int y0 = (int)fy, x0i = (int)fx;
        int y1 = y0 + 1, x1i = x0i + 1;
        bool vy0 = (y0 >= 0) && (y0 < HI), vy1 = (y1 >= 0) && (y1 < HI);
        bool vx0 = (x0i >= 0) && (x0i < WI), vx1 = (x1i >= 0) && (x1i < WI);
        lw00[p] = (vy0 && vx0) ? wy0 * wx0 * m : 0.f;
        lw01[p] = (vy0 && vx1) ? wy0 * wx1 * m : 0.f;
        lw10[p] = (vy1 && vx0) ? wy1 * wx0 * m : 0.f;
        lw11[p] = (vy1 && vx1) ? wy1 * wx1 * m : 0.f;
        ly0[p] = (y0 < 0 ? 0 : (y0 > HI-1 ? HI-1 : y0)) * WI;
        ly1[p] = (y1 < 0 ? 0 : (y1 > HI-1 ? HI-1 : y1)) * WI;
        lx0[p] = (x0i < 0 ? 0 : (x0i > WI-1 ? WI-1 : x0i));
        lx1[p] = (x1i < 0 ? 0 : (x1i > WI-1 ? WI-1 : x1i));
    }
    __syncthreads();

    const float* xb = x + (size_t)b * CI * HI * WI;
    #pragma unroll 4
    for (int it = 0; it < 36; ++it) {
        int i = t + it * 256;
        int c = i / 144;
        int p = i - c * 144;
        int px_id = p / 9, k = p - px_id * 9;
        const float* xc = xb + c * (HI * WI);
        int r0 = ly0[p], r1 = ly1[p], c0 = lx0[p], c1 = lx1[p];
        float v = lw00[p] * xc[r0 + c0] + lw01[p] * xc[r0 + c1]
                + lw10[p] * xc[r1 + c0] + lw11[p] * xc[r1 + c1];
        s[px_id * KCP + c * 9 + k] = f2bf(v);
    }
    __syncthreads();

    const int lane = t & 63, wv = t >> 6;
    const int q = lane >> 4, l15 = lane & 15;
    const u16* sp  = &s[l15 * KCP + q * 8];
    const int oc0 = wv * 32 + l15;
    const int oc1 = oc0 + 16;
    const u16* wp0 = wbf + oc0 * KCP + q * 8;
    const u16* wp1 = wbf + oc1 * KCP + q * 8;
    f32x4 acc0 = {0.f, 0.f, 0.f, 0.f};
    f32x4 acc1 = {0.f, 0.f, 0.f, 0.f};
    #pragma unroll
    for (int kt = 0; kt < 18; ++kt) {
        bf16x8 a  = *(const bf16x8*)(sp  + kt * 32);
        bf16x8 b0 = *(const bf16x8*)(wp0 + kt * 32);
        bf16x8 b1 = *(const bf16x8*)(wp1 + kt * 32);
        acc0 = __builtin_amdgcn_mfma_f32_16x16x32_bf16(a, b0, acc0, 0, 0, 0);
        acc1 = __builtin_amdgcn_mfma_f32_16x16x32_bf16(a, b1, acc1, 0, 0, 0);
    }
    const float bi0 = bias[oc0], bi1 = bias[oc1];
    const int px = q * 4;
    float* op0 = out + (((size_t)b * OC + oc0) * HO + ho) * WO + wo0 + px;
    float* op1 = out + (((size_t)b * OC + oc1) * HO + ho) * WO + wo0 + px;
    *(float4*)op0 = make_float4(acc0[0] + bi0, acc0[1] + bi0, acc0[2] + bi0, acc0[3] + bi0);
    *(float4*)op1 = make_float4(acc1[0] + bi1, acc1[1] + bi1, acc1[2] + bi1, acc1[3] + bi1);
}

extern "C" void kernel_launch(void* const* d_in, const int* in_sizes, int n_in,
                              void* d_out, int out_size, void* d_ws, size_t ws_size,
                              hipStream_t stream) {
    const float* x        = (const float*)d_in[0];
    const float* offset_w = (const float*)d_in[1];
    const float* offset_b = (const float*)d_in[2];
    const float* weight   = (const float*)d_in[3];
    const float* bias     = (const float*)d_in[4];
    float* out = (float*)d_out;

    const size_t xT_full = (size_t)NB * HI * WI * CI * 2;   // 67,108,864
    const size_t om_full = (size_t)NB * 27 * HO * WO * 4;   // 14,155,776
    const size_t xT_b    = (size_t)HI * WI * CI * 2;        //  8,388,608
    const size_t om_b    = (size_t)27 * HO * WO * 4;        //  1,769,472
    const size_t wsz     = (size_t)(OC + 32) * KCP * 2;     //    186,880
    const int nwb = (int)(((OC + 32) * KCP + 255) / 256);

    if (ws_size >= xT_full + om_full + wsz) {
        u16*   xT  = (u16*)d_ws;
        float* om  = (float*)((char*)d_ws + xT_full);
        u16*   wbf = (u16*)((char*)d_ws + xT_full + om_full);
        u16*   wob = wbf + OC * KCP;
        hipLaunchKernelGGL(k_wconv, dim3(nwb), dim3(256), 0, stream, weight, offset_w, wbf, wob);
        hipLaunchKernelGGL(k_tr,   dim3(4, 256, NB), dim3(256), 0, stream, x, xT, 0);
        hipLaunchKernelGGL(k_off,  dim3(4, 128, NB), dim3(256), 0, stream, xT, wob, offset_b, om);
        hipLaunchKernelGGL(k_main, dim3(8, 128, NB), dim3(256), 0, stream, x, om, wbf, bias, out, 0);
    } else {
        u16*   xT  = (u16*)d_ws;
        float* om  = (float*)((char*)d_ws + xT_b);
        u16*   wbf = (u16*)((char*)d_ws + xT_b + om_b);
        u16*   wob = wbf + OC * KCP;
        hipLaunchKernelGGL(k_wconv, dim3(nwb), dim3(256), 0, stream, weight, offset_w, wbf, wob);
        for (int b = 0; b < NB; ++b) {
            hipLaunchKernelGGL(k_tr,   dim3(4, 256, 1), dim3(256), 0, stream, x, xT, b);
            hipLaunchKernelGGL(k_off,  dim3(4, 128, 1), dim3(256), 0, stream, xT, wob, offset_b, om);
            hipLaunchKernelGGL(k_main, dim3(8, 128, 1), dim3(256), 0, stream, x, om, wbf, bias, out, b);
        }
    }
}

// Round 5
// 361.452 us; speedup vs baseline: 2.8948x; 1.7336x over previous
//
#include <hip/hip_runtime.h>

typedef unsigned short u16;
typedef __attribute__((ext_vector_type(8))) short bf16x8;
typedef __attribute__((ext_vector_type(8))) unsigned short u16x8;
typedef __attribute__((ext_vector_type(4))) float f32x4;

#define HI 256
#define WI 256
#define CI 64
#define OC 128
#define HO 128
#define WO 128
#define NB 8
#define KC 576
#define KCP 584          // +8 pad to break LDS bank stride
#define TW 16            // k_main pixel tile (verified r0/r4 structure)

static __device__ __forceinline__ u16 f2bf(float f) {   // RNE
    union { float f; unsigned u; } v; v.f = f;
    return (u16)((v.u + 0x7FFFu + ((v.u >> 16) & 1u)) >> 16);
}
static __device__ __forceinline__ float bf2f(u16 h) {
    union { unsigned u; float f; } v; v.u = ((unsigned)h) << 16;
    return v.f;
}

// ---- weights: wbf (main, kc=c*9+k), wob (offset, kc=k*64+c) — r4 verbatim ----
__global__ __launch_bounds__(256) void k_wconv(const float* __restrict__ w,
                                               const float* __restrict__ ow,
                                               u16* __restrict__ wbf, u16* __restrict__ wob) {
    int i = blockIdx.x * 256 + threadIdx.x;
    const int NW = OC * KCP;
    if (i < NW) {
        int oc = i / KCP, kc = i - oc * KCP;
        float v = (kc < KC) ? w[oc * KC + kc] : 0.f;       // flat reshape: kc = c*9+k
        wbf[i] = f2bf(v);
    } else {
        int i2 = i - NW;
        if (i2 < 32 * KCP) {
            int oc = i2 / KCP, kc = i2 - oc * KCP;
            float v = 0.f;
            if (oc < 27 && kc < KC) { int k = kc >> 6, c = kc & 63; v = ow[(oc * CI + c) * 9 + k]; }
            wob[i2] = f2bf(v);
        }
    }
}

// ---- transpose: x[b][c][h][w] fp32 -> xT[bz][h][w][c] bf16 — r4 verbatim ----
__global__ __launch_bounds__(256) void k_tr(const float* __restrict__ x, u16* __restrict__ xT, int b0) {
    __shared__ u16 tile[64 * 68];
    const int t = threadIdx.x;
    const int w0 = blockIdx.x * 64;
    const int h  = blockIdx.y;
    const int bz = blockIdx.z;
    const float* xp = x + ((size_t)(b0 + bz) * CI) * (HI * WI) + h * WI + w0;
    #pragma unroll
    for (int i = 0; i < 4; ++i) {
        int c = i * 16 + (t >> 4);
        int w = (t & 15) * 4;
        float4 v = *(const float4*)(xp + (size_t)c * (HI * WI) + w);
        tile[(w + 0) * 68 + c] = f2bf(v.x);
        tile[(w + 1) * 68 + c] = f2bf(v.y);
        tile[(w + 2) * 68 + c] = f2bf(v.z);
        tile[(w + 3) * 68 + c] = f2bf(v.w);
    }
    __syncthreads();
    u16* op = xT + (size_t)bz * (HI * WI * CI) + ((size_t)h * WI + w0) * CI;
    #pragma unroll
    for (int j = 0; j < 4; ++j) {
        int w = j * 16 + (t >> 4);
        int c = (t & 15) * 4;
        *(ushort4*)(op + (size_t)w * CI + c) = *(const ushort4*)&tile[w * 68 + c];
    }
}

// ---- offset conv via MFMA — r4 verbatim ----
__global__ __launch_bounds__(256) void k_off(const u16* __restrict__ xT,
                                             const u16* __restrict__ wob,
                                             const float* __restrict__ ob,
                                             float* __restrict__ om) {
    __shared__ u16 s[32 * KCP];
    __shared__ int atab[288];
    __shared__ float red[2][2][64][4];
    const int t = threadIdx.x;
    const int wo0 = blockIdx.x * 32;
    const int ho = blockIdx.y;
    const int bz = blockIdx.z;
    const u16* xb = xT + (size_t)bz * (HI * WI * CI);

    for (int p = t; p < 288; p += 256) {
        int px = p / 9, k = p - px * 9;
        int ky = k / 3, kx = k - ky * 3;
        int y  = ho * 2 - 1 + ky;
        int xx = (wo0 + px) * 2 - 1 + kx;
        bool valid = ((unsigned)y < HI) && ((unsigned)xx < WI);
        atab[p] = valid ? (y * WI + xx) * CI : -1;
    }
    __syncthreads();

    #pragma unroll 3
    for (int it = 0; it < 9; ++it) {
        int idx = it * 256 + t;
        int p = idx >> 3, c8 = idx & 7;
        int a = atab[p];
        u16x8 v = {0, 0, 0, 0, 0, 0, 0, 0};
        if (a >= 0) v = *(const u16x8*)(xb + a + c8 * 8);
        int px = p / 9, k = p - px * 9;
        *(u16x8*)&s[px * KCP + k * 64 + c8 * 8] = v;
    }
    __syncthreads();

    const int lane = t & 63, wv = t >> 6;
    const int q = lane >> 4, l15 = lane & 15;
    const int ph = wv & 1, kh = wv >> 1;
    const u16* sp  = &s[(ph * 16 + l15) * KCP + kh * 288 + q * 8];
    const u16* wp0 = wob + l15 * KCP + kh * 288 + q * 8;
    const u16* wp1 = wob + (16 + l15) * KCP + kh * 288 + q * 8;
    f32x4 acc0 = {0.f, 0.f, 0.f, 0.f}, acc1 = {0.f, 0.f, 0.f, 0.f};
    #pragma unroll
    for (int kt = 0; kt < 9; ++kt) {
        bf16x8 a  = *(const bf16x8*)(sp  + kt * 32);
        bf16x8 b0 = *(const bf16x8*)(wp0 + kt * 32);
        bf16x8 b1 = *(const bf16x8*)(wp1 + kt * 32);
        acc0 = __builtin_amdgcn_mfma_f32_16x16x32_bf16(a, b0, acc0, 0, 0, 0);
        acc1 = __builtin_amdgcn_mfma_f32_16x16x32_bf16(a, b1, acc1, 0, 0, 0);
    }
    if (kh == 1) {
        #pragma unroll
        for (int r = 0; r < 4; ++r) { red[ph][0][lane][r] = acc0[r]; red[ph][1][lane][r] = acc1[r]; }
    }
    __syncthreads();
    if (kh == 0) {
        #pragma unroll
        for (int r = 0; r < 4; ++r) { acc0[r] += red[ph][0][lane][r]; acc1[r] += red[ph][1][lane][r]; }
        const int wo = wo0 + ph * 16 + q * 4;
        float bv0 = ob[l15];
        float* o0 = om + ((size_t)(bz * 27 + l15) * HO + ho) * WO + wo;
        *(float4*)o0 = make_float4(acc0[0] + bv0, acc0[1] + bv0, acc0[2] + bv0, acc0[3] + bv0);
        if (l15 < 11) {
            float bv1 = ob[16 + l15];
            float* o1 = om + ((size_t)(bz * 27 + 16 + l15) * HO + ho) * WO + wo;
            *(float4*)o1 = make_float4(acc1[0] + bv1, acc1[1] + bv1, acc1[2] + bv1, acc1[3] + bv1);
        }
    }
}

// ---- main: r4 skeleton verbatim; ONLY the gather loads changed to vectorized xT ----
__global__ __launch_bounds__(256) void k_main(const u16* __restrict__ xT,
                                              const float* __restrict__ om,
                                              const u16* __restrict__ wbf,
                                              const float* __restrict__ bias,
                                              float* __restrict__ out, int b0) {
    __shared__ u16 s[TW * KCP];
    __shared__ int   la00[144], la01[144], la10[144], la11[144];  // corner element addrs (pixel*CI)
    __shared__ float lw00[144], lw01[144], lw10[144], lw11[144];

    const int t = threadIdx.x;
    const int wo0 = blockIdx.x * TW;
    const int ho = blockIdx.y;
    const int bz = blockIdx.z;
    const int b = b0 + bz;

    if (t < 144) {
        const int p = t;
        const int px_id = p / 9, k = p - px_id * 9;
        const int wo = wo0 + px_id;
        const size_t base = ((size_t)bz * 27) * (HO * WO) + ho * WO + wo;
        float oxv = om[base + (size_t)k * (HO * WO)];
        float oyv = om[base + (size_t)(9 + k) * (HO * WO)];
        float omm = om[base + (size_t)(18 + k) * (HO * WO)];
        float m = 1.f / (1.f + __expf(-omm));
        float py  = oyv + (float)(k / 3) + (float)(ho * 2 - 1);
        float pxf = oxv + (float)(k % 3) + (float)(wo * 2 - 1);
        float fy = floorf(py), fx = floorf(pxf);
        float wy1 = py - fy, wx1 = pxf - fx;
        float wy0 = 1.f - wy1, wx0 = 1.f - wx1;
        int y0 = (int)fy, x0i = (int)fx;
        int y1 = y0 + 1, x1i = x0i + 1;
        bool vy0 = (y0 >= 0) && (y0 < HI), vy1 = (y1 >= 0) && (y1 < HI);
        bool vx0 = (x0i >= 0) && (x0i < WI), vx1 = (x1i >= 0) && (x1i < WI);
        lw00[p] = (vy0 && vx0) ? wy0 * wx0 * m : 0.f;
        lw01[p] = (vy0 && vx1) ? wy0 * wx1 * m : 0.f;
        lw10[p] = (vy1 && vx0) ? wy1 * wx0 * m : 0.f;
        lw11[p] = (vy1 && vx1) ? wy1 * wx1 * m : 0.f;
        int y0c = (y0 < 0 ? 0 : (y0 > HI-1 ? HI-1 : y0));
        int y1c = (y1 < 0 ? 0 : (y1 > HI-1 ? HI-1 : y1));
        int x0c = (x0i < 0 ? 0 : (x0i > WI-1 ? WI-1 : x0i));
        int x1c = (x1i < 0 ? 0 : (x1i > WI-1 ? WI-1 : x1i));
        la00[p] = (y0c * WI + x0c) * CI;
        la01[p] = (y0c * WI + x1c) * CI;
        la10[p] = (y1c * WI + x0c) * CI;
        la11[p] = (y1c * WI + x1c) * CI;
    }
    __syncthreads();

    // gather: 144 (px,k) pairs x 8 channel-chunks = 1152 items; 4x u16x8 loads each
    const u16* xb = xT + (size_t)bz * (HI * WI * CI);
    for (int i = t; i < 1152; i += 256) {
        int p = i >> 3;
        int co = (i & 7) * 8;
        int px_id = p / 9, k = p - px_id * 9;
        float w00 = lw00[p], w01 = lw01[p], w10 = lw10[p], w11 = lw11[p];
        u16x8 va = *(const u16x8*)(xb + la00[p] + co);
        u16x8 vb = *(const u16x8*)(xb + la01[p] + co);
        u16x8 vc = *(const u16x8*)(xb + la10[p] + co);
        u16x8 vd = *(const u16x8*)(xb + la11[p] + co);
        u16* sd = &s[px_id * KCP + k];
        #pragma unroll
        for (int j = 0; j < 8; ++j) {
            float v = w00 * bf2f(va[j]) + w01 * bf2f(vb[j])
                    + w10 * bf2f(vc[j]) + w11 * bf2f(vd[j]);
            sd[(co + j) * 9] = f2bf(v);      // kc = c*9 + k, matching wbf
        }
    }
    __syncthreads();

    // MFMA phase — r4 verbatim
    const int lane = t & 63, wv = t >> 6;
    const int q = lane >> 4, l15 = lane & 15;
    const u16* sp  = &s[l15 * KCP + q * 8];
    const int oc0 = wv * 32 + l15;
    const int oc1 = oc0 + 16;
    const u16* wp0 = wbf + oc0 * KCP + q * 8;
    const u16* wp1 = wbf + oc1 * KCP + q * 8;
    f32x4 acc0 = {0.f, 0.f, 0.f, 0.f};
    f32x4 acc1 = {0.f, 0.f, 0.f, 0.f};
    #pragma unroll
    for (int kt = 0; kt < 18; ++kt) {
        bf16x8 a  = *(const bf16x8*)(sp  + kt * 32);
        bf16x8 b0 = *(const bf16x8*)(wp0 + kt * 32);
        bf16x8 b1 = *(const bf16x8*)(wp1 + kt * 32);
        acc0 = __builtin_amdgcn_mfma_f32_16x16x32_bf16(a, b0, acc0, 0, 0, 0);
        acc1 = __builtin_amdgcn_mfma_f32_16x16x32_bf16(a, b1, acc1, 0, 0, 0);
    }
    const float bi0 = bias[oc0], bi1 = bias[oc1];
    const int px = q * 4;
    float* op0 = out + (((size_t)b * OC + oc0) * HO + ho) * WO + wo0 + px;
    float* op1 = out + (((size_t)b * OC + oc1) * HO + ho) * WO + wo0 + px;
    *(float4*)op0 = make_float4(acc0[0] + bi0, acc0[1] + bi0, acc0[2] + bi0, acc0[3] + bi0);
    *(float4*)op1 = make_float4(acc1[0] + bi1, acc1[1] + bi1, acc1[2] + bi1, acc1[3] + bi1);
}

extern "C" void kernel_launch(void* const* d_in, const int* in_sizes, int n_in,
                              void* d_out, int out_size, void* d_ws, size_t ws_size,
                              hipStream_t stream) {
    const float* x        = (const float*)d_in[0];
    const float* offset_w = (const float*)d_in[1];
    const float* offset_b = (const float*)d_in[2];
    const float* weight   = (const float*)d_in[3];
    const float* bias     = (const float*)d_in[4];
    float* out = (float*)d_out;

    const size_t xT_full = (size_t)NB * HI * WI * CI * 2;   // 67,108,864
    const size_t om_full = (size_t)NB * 27 * HO * WO * 4;   // 14,155,776
    const size_t xT_b    = (size_t)HI * WI * CI * 2;        //  8,388,608
    const size_t om_b    = (size_t)27 * HO * WO * 4;        //  1,769,472
    const size_t wsz     = (size_t)(OC + 32) * KCP * 2;     //    186,880
    const int nwb = (int)(((OC + 32) * KCP + 255) / 256);

    if (ws_size >= xT_full + om_full + wsz) {
        u16*   xT  = (u16*)d_ws;
        float* om  = (float*)((char*)d_ws + xT_full);
        u16*   wbf = (u16*)((char*)d_ws + xT_full + om_full);
        u16*   wob = wbf + OC * KCP;
        hipLaunchKernelGGL(k_wconv, dim3(nwb), dim3(256), 0, stream, weight, offset_w, wbf, wob);
        hipLaunchKernelGGL(k_tr,   dim3(4, 256, NB), dim3(256), 0, stream, x, xT, 0);
        hipLaunchKernelGGL(k_off,  dim3(4, 128, NB), dim3(256), 0, stream, xT, wob, offset_b, om);
        hipLaunchKernelGGL(k_main, dim3(8, 128, NB), dim3(256), 0, stream, xT, om, wbf, bias, out, 0);
    } else {
        u16*   xT  = (u16*)d_ws;
        float* om  = (float*)((char*)d_ws + xT_b);
        u16*   wbf = (u16*)((char*)d_ws + xT_b + om_b);
        u16*   wob = wbf + OC * KCP;
        hipLaunchKernelGGL(k_wconv, dim3(nwb), dim3(256), 0, stream, weight, offset_w, wbf, wob);
        for (int b = 0; b < NB; ++b) {
            hipLaunchKernelGGL(k_tr,   dim3(4, 256, 1), dim3(256), 0, stream, x, xT, b);
            hipLaunchKernelGGL(k_off,  dim3(4, 128, 1), dim3(256), 0, stream, xT, wob, offset_b, om);
            hipLaunchKernelGGL(k_main, dim3(8, 128, 1), dim3(256), 0, stream, xT, om, wbf, bias, out, b);
        }
    }
}